// Round 1
// baseline (95.845 us; speedup 1.0000x reference)
//
#include <hip/hip_runtime.h>
#include <hip/hip_bf16.h>

typedef __attribute__((ext_vector_type(8))) short short8;
typedef __attribute__((ext_vector_type(8))) unsigned short ushort8;
typedef __attribute__((ext_vector_type(16))) float f32x16;

#define LOG2E 1.4426950408889634f
#define MFMA32(a, b, c) __builtin_amdgcn_mfma_f32_32x32x16_bf16((a), (b), (c), 0, 0, 0)
#define ZERO16 {0.f,0.f,0.f,0.f,0.f,0.f,0.f,0.f,0.f,0.f,0.f,0.f,0.f,0.f,0.f,0.f}

__device__ __forceinline__ unsigned short bfbits(float f) {
    __hip_bfloat16 h = __float2bfloat16(f);
    return __builtin_bit_cast(unsigned short, h);
}
__device__ __forceinline__ float bf2f(unsigned short u) {
    unsigned v = ((unsigned)u) << 16;
    return __builtin_bit_cast(float, v);
}

// ---- kernel 0: W[k][d] -> WT[d][k] as bf16 hi/lo -------------------------------
__global__ __launch_bounds__(128) void gat_wt(const float* __restrict__ W,
                                              unsigned short* __restrict__ WTh,
                                              unsigned short* __restrict__ WTl) {
    __shared__ float ws_[8][128];
    const int k0 = blockIdx.x * 8;
    const int d = threadIdx.x;
#pragma unroll
    for (int i = 0; i < 8; ++i) ws_[i][d] = W[(k0 + i) * 128 + d];
    __syncthreads();
    ushort8 vh, vl;
#pragma unroll
    for (int i = 0; i < 8; ++i) {
        float f = ws_[i][d];
        unsigned short hb = bfbits(f);
        vh[i] = hb;
        vl[i] = bfbits(f - bf2f(hb));
    }
    *(ushort8*)(WTh + d * 128 + k0) = vh;
    *(ushort8*)(WTl + d * 128 + k0) = vl;
}

// ---- kernel 1: h = x@W via MFMA (hi/lo split); writes HT^T bf16 hi/lo, f1l, f2l -
__global__ __launch_bounds__(256) void gat_h(const float* __restrict__ x,
                                             const unsigned short* __restrict__ WTh,
                                             const unsigned short* __restrict__ WTl,
                                             const float* __restrict__ a,
                                             unsigned short* __restrict__ HTh,
                                             unsigned short* __restrict__ HTl,
                                             float* __restrict__ f1l,
                                             float* __restrict__ f2l) {
    __shared__ float hs[32][130];
    __shared__ float red[2][32][8];
    const int tid = threadIdx.x;
    const int lane = tid & 63;
    const int wv = tid >> 6;          // 4 waves, one 32-col tile each
    const int l31 = lane & 31;
    const int koff = (lane >> 5) << 3;
    const int t0 = blockIdx.x * 32;   // global row (8*2048 rows total)
    const int rg = t0 + l31;
    const int c0 = wv * 32;

    f32x16 p0 = ZERO16, p1 = ZERO16, p2 = ZERO16;  // xhi*Whi, xlo*Whi, xhi*Wlo
    const float* xp = x + (size_t)rg * 128 + koff;
    const unsigned short* bph = WTh + (c0 + l31) * 128 + koff;
    const unsigned short* bpl = WTl + (c0 + l31) * 128 + koff;

#pragma unroll
    for (int kk = 0; kk < 128; kk += 16) {
        float4 xa = *(const float4*)(xp + kk);
        float4 xb = *(const float4*)(xp + kk + 4);
        float fv[8] = {xa.x, xa.y, xa.z, xa.w, xb.x, xb.y, xb.z, xb.w};
        short8 xh, xl;
#pragma unroll
        for (int q = 0; q < 8; ++q) {
            unsigned short hb = bfbits(fv[q]);
            xh[q] = (short)hb;
            xl[q] = (short)bfbits(fv[q] - bf2f(hb));
        }
        short8 bh = __builtin_bit_cast(short8, *(const ushort8*)(bph + kk));
        short8 bl = __builtin_bit_cast(short8, *(const ushort8*)(bpl + kk));
        p0 = MFMA32(xh, bh, p0);
        p1 = MFMA32(xl, bh, p1);
        p2 = MFMA32(xh, bl, p2);
    }
#pragma unroll
    for (int r = 0; r < 16; ++r) {
        int crow = (r & 3) + 8 * (r >> 2) + 4 * (lane >> 5);
        hs[crow][c0 + l31] = p0[r] + p1[r] + p2[r];
    }
    __syncthreads();
    // transposed HT writes: thread owns one d, 16 consecutive t's
    {
        const int d = tid & 127, half = tid >> 7;
        ushort8 h0, h1, l0, l1;
#pragma unroll
        for (int j = 0; j < 8; ++j) {
            float f = hs[half * 16 + j][d];
            unsigned short hb = bfbits(f);
            h0[j] = hb;
            l0[j] = bfbits(f - bf2f(hb));
        }
#pragma unroll
        for (int j = 0; j < 8; ++j) {
            float f = hs[half * 16 + 8 + j][d];
            unsigned short hb = bfbits(f);
            h1[j] = hb;
            l1[j] = bfbits(f - bf2f(hb));
        }
        const int b = t0 >> 11;
        const int tloc = t0 & 2047;
        size_t base = ((size_t)(b * 128 + d)) * 2048 + tloc + half * 16;
        *(ushort8*)(HTh + base) = h0;
        *(ushort8*)(HTh + base + 8) = h1;
        *(ushort8*)(HTl + base) = l0;
        *(ushort8*)(HTl + base + 8) = l1;
    }
    // f1 = h@a1, f2 = h@a2 (pre-scaled by log2e)
    {
        const int r = tid & 31, seg = tid >> 5;
        float s1 = 0.f, s2 = 0.f;
#pragma unroll
        for (int i = 0; i < 16; ++i) {
            float hv = hs[r][seg * 16 + i];
            s1 += hv * a[seg * 16 + i];
            s2 += hv * a[128 + seg * 16 + i];
        }
        red[0][r][seg] = s1;
        red[1][r][seg] = s2;
    }
    __syncthreads();
    if (tid < 32) {
        float s1 = 0.f, s2 = 0.f;
#pragma unroll
        for (int g = 0; g < 8; ++g) { s1 += red[0][tid][g]; s2 += red[1][tid][g]; }
        f1l[t0 + tid] = s1 * LOG2E;
        f2l[t0 + tid] = s2 * LOG2E;
    }
}

// ---- kernel 1b: per-batch max of f2l ------------------------------------------
__global__ __launch_bounds__(256) void gat_f2max(const float* __restrict__ f2l,
                                                 float* __restrict__ f2m) {
    const int b = blockIdx.x;
    const int tid = threadIdx.x;
    float m = -3.4e38f;
    for (int j = tid; j < 2048; j += 256) m = fmaxf(m, f2l[b * 2048 + j]);
#pragma unroll
    for (int o = 1; o < 64; o <<= 1) m = fmaxf(m, __shfl_xor(m, o, 64));
    __shared__ float wm_[4];
    if ((tid & 63) == 0) wm_[tid >> 6] = m;
    __syncthreads();
    if (tid == 0) f2m[b] = fmaxf(fmaxf(wm_[0], wm_[1]), fmaxf(wm_[2], wm_[3]));
}

// ---- kernel 2: fused P-gen + softmax-denominator + P@H (hi+lo) -----------------
__global__ __launch_bounds__(256) void gat_attn(const unsigned short* __restrict__ HTh,
                                                const unsigned short* __restrict__ HTl,
                                                const float* __restrict__ f1l,
                                                const float* __restrict__ f2l,
                                                const float* __restrict__ f2m,
                                                float* __restrict__ out) {
    __shared__ float invs[64];
    const int bid = blockIdx.x;
    const int b = bid & 7;          // batch == XCD for L2 locality
    const int tile = bid >> 3;      // 0..31
    const int tid = threadIdx.x;
    const int lane = tid & 63;
    const int wv = tid >> 6;
    const int wm = wv >> 1, wn = wv & 1;
    const int l31 = lane & 31;
    const int koff = (lane >> 5) << 3;

    const int rowg = tile * 64 + wm * 32 + l31;
    const float f1m = f1l[b * 2048 + rowg];
    const float tm = f1m + f2m[b];
    const float ml = fmaxf(tm, 0.2f * tm);   // exact row max (lrelu monotonic)

    const float* f2b = f2l + b * 2048;
    const int c0 = wn * 64;
    const unsigned short* ph0 = HTh + ((size_t)(b * 128 + c0 + l31)) * 2048 + koff;
    const unsigned short* ph1 = ph0 + 32 * 2048;
    const unsigned short* pl0 = HTl + ((size_t)(b * 128 + c0 + l31)) * 2048 + koff;
    const unsigned short* pl1 = pl0 + 32 * 2048;

    f32x16 ah0 = ZERO16, ah1 = ZERO16, al0 = ZERO16, al1 = ZERO16;
    float sp = 0.f;

    // register double-buffer prefetch
    float4 fva = *(const float4*)(f2b + koff);
    float4 fvb = *(const float4*)(f2b + koff + 4);
    uint4 vh0 = *(const uint4*)(ph0);
    uint4 vh1 = *(const uint4*)(ph1);
    uint4 vl0 = *(const uint4*)(pl0);
    uint4 vl1 = *(const uint4*)(pl1);

    for (int j0 = 0; j0 < 2048; j0 += 16) {
        const int jn = (j0 + 16) & 2047;  // last iter harmlessly reloads j=0
        float4 nfa = *(const float4*)(f2b + jn + koff);
        float4 nfb = *(const float4*)(f2b + jn + koff + 4);
        uint4 nh0 = *(const uint4*)(ph0 + jn);
        uint4 nh1 = *(const uint4*)(ph1 + jn);
        uint4 nl0 = *(const uint4*)(pl0 + jn);
        uint4 nl1 = *(const uint4*)(pl1 + jn);

        float fv[8] = {fva.x, fva.y, fva.z, fva.w, fvb.x, fvb.y, fvb.z, fvb.w};
        short8 af;
#pragma unroll
        for (int q = 0; q < 8; ++q) {
            float t = f1m + fv[q];
            float e = fmaxf(t, 0.2f * t);           // == lrelu(t), alpha=0.2
            float p = __builtin_amdgcn_exp2f(e - ml);
            sp += p;
            af[q] = (short)bfbits(p);
        }
        ah0 = MFMA32(af, __builtin_bit_cast(short8, vh0), ah0);
        ah1 = MFMA32(af, __builtin_bit_cast(short8, vh1), ah1);
        al0 = MFMA32(af, __builtin_bit_cast(short8, vl0), al0);
        al1 = MFMA32(af, __builtin_bit_cast(short8, vl1), al1);

        fva = nfa; fvb = nfb;
        vh0 = nh0; vh1 = nh1; vl0 = nl0; vl1 = nl1;
    }

    float spo = __shfl_xor(sp, 32, 64);
    float linv = 1.0f / (sp + spo);
    if (wn == 0 && lane < 32) invs[wm * 32 + l31] = linv;
    __syncthreads();

    const size_t obase = ((size_t)b * 2048 + (size_t)tile * 64 + wm * 32) * 128 + c0 + l31;
#pragma unroll
    for (int r = 0; r < 16; ++r) {
        int crow = (r & 3) + 8 * (r >> 2) + 4 * (lane >> 5);
        float inv = invs[wm * 32 + crow];
        out[obase + (size_t)crow * 128] = (ah0[r] + al0[r]) * inv;
        out[obase + (size_t)crow * 128 + 32] = (ah1[r] + al1[r]) * inv;
    }
}

extern "C" void kernel_launch(void* const* d_in, const int* in_sizes, int n_in,
                              void* d_out, int out_size, void* d_ws, size_t ws_size,
                              hipStream_t stream) {
    const float* x = (const float*)d_in[0];
    const float* W = (const float*)d_in[1];
    const float* a = (const float*)d_in[2];
    float* out = (float*)d_out;

    unsigned short* WTh = (unsigned short*)d_ws;
    unsigned short* WTl = WTh + 128 * 128;
    unsigned short* HTh = WTl + 128 * 128;
    unsigned short* HTl = HTh + (size_t)8 * 128 * 2048;
    float* f1l = (float*)(HTl + (size_t)8 * 128 * 2048);
    float* f2l = f1l + 16384;
    float* f2m = f2l + 16384;

    gat_wt<<<16, 128, 0, stream>>>(W, WTh, WTl);
    gat_h<<<512, 256, 0, stream>>>(x, WTh, WTl, a, HTh, HTl, f1l, f2l);
    gat_f2max<<<8, 256, 0, stream>>>(f2l, f2m);
    gat_attn<<<256, 256, 0, stream>>>(HTh, HTl, f1l, f2l, f2m, out);
}

// Round 2
// 64.791 us; speedup vs baseline: 1.4793x; 1.4793x over previous
//
#include <hip/hip_runtime.h>
#include <hip/hip_bf16.h>

typedef __attribute__((ext_vector_type(8))) short short8;
typedef __attribute__((ext_vector_type(8))) unsigned short ushort8;
typedef __attribute__((ext_vector_type(16))) float f32x16;

#define LOG2E 1.4426950408889634f
#define MFMA32(a, b, c) __builtin_amdgcn_mfma_f32_32x32x16_bf16((a), (b), (c), 0, 0, 0)
#define ZERO16 {0.f,0.f,0.f,0.f,0.f,0.f,0.f,0.f,0.f,0.f,0.f,0.f,0.f,0.f,0.f,0.f}

__device__ __forceinline__ unsigned short bfbits(float f) {
    __hip_bfloat16 h = __float2bfloat16(f);
    return __builtin_bit_cast(unsigned short, h);
}
__device__ __forceinline__ float bf2f(unsigned short u) {
    unsigned v = ((unsigned)u) << 16;
    return __builtin_bit_cast(float, v);
}

// ---- kernel 0: W[k][d] -> WT[d][k] as bf16 hi/lo -------------------------------
__global__ __launch_bounds__(128) void gat_wt(const float* __restrict__ W,
                                              unsigned short* __restrict__ WTh,
                                              unsigned short* __restrict__ WTl) {
    __shared__ float ws_[8][128];
    const int k0 = blockIdx.x * 8;
    const int d = threadIdx.x;
#pragma unroll
    for (int i = 0; i < 8; ++i) ws_[i][d] = W[(k0 + i) * 128 + d];
    __syncthreads();
    ushort8 vh, vl;
#pragma unroll
    for (int i = 0; i < 8; ++i) {
        float f = ws_[i][d];
        unsigned short hb = bfbits(f);
        vh[i] = hb;
        vl[i] = bfbits(f - bf2f(hb));
    }
    *(ushort8*)(WTh + d * 128 + k0) = vh;
    *(ushort8*)(WTl + d * 128 + k0) = vl;
}

// ---- kernel 1: h = x@W via MFMA (hi/lo split); writes HT^T bf16 hi, f1l, f2l ---
__global__ __launch_bounds__(256) void gat_h(const float* __restrict__ x,
                                             const unsigned short* __restrict__ WTh,
                                             const unsigned short* __restrict__ WTl,
                                             const float* __restrict__ a,
                                             unsigned short* __restrict__ HTh,
                                             float* __restrict__ f1l,
                                             float* __restrict__ f2l) {
    __shared__ float hs[32][130];
    __shared__ float red[2][32][8];
    const int tid = threadIdx.x;
    const int lane = tid & 63;
    const int wv = tid >> 6;          // 4 waves, one 32-col tile each
    const int l31 = lane & 31;
    const int koff = (lane >> 5) << 3;
    const int t0 = blockIdx.x * 32;   // global row (8*2048 rows total)
    const int rg = t0 + l31;
    const int c0 = wv * 32;

    f32x16 p0 = ZERO16, p1 = ZERO16, p2 = ZERO16;  // xhi*Whi, xlo*Whi, xhi*Wlo
    const float* xp = x + (size_t)rg * 128 + koff;
    const unsigned short* bph = WTh + (c0 + l31) * 128 + koff;
    const unsigned short* bpl = WTl + (c0 + l31) * 128 + koff;

#pragma unroll
    for (int kk = 0; kk < 128; kk += 16) {
        float4 xa = *(const float4*)(xp + kk);
        float4 xb = *(const float4*)(xp + kk + 4);
        float fv[8] = {xa.x, xa.y, xa.z, xa.w, xb.x, xb.y, xb.z, xb.w};
        short8 xh, xl;
#pragma unroll
        for (int q = 0; q < 8; ++q) {
            unsigned short hb = bfbits(fv[q]);
            xh[q] = (short)hb;
            xl[q] = (short)bfbits(fv[q] - bf2f(hb));
        }
        short8 bh = __builtin_bit_cast(short8, *(const ushort8*)(bph + kk));
        short8 bl = __builtin_bit_cast(short8, *(const ushort8*)(bpl + kk));
        p0 = MFMA32(xh, bh, p0);
        p1 = MFMA32(xl, bh, p1);
        p2 = MFMA32(xh, bl, p2);
    }
#pragma unroll
    for (int r = 0; r < 16; ++r) {
        int crow = (r & 3) + 8 * (r >> 2) + 4 * (lane >> 5);
        hs[crow][c0 + l31] = p0[r] + p1[r] + p2[r];
    }
    __syncthreads();
    // transposed HT writes: thread owns one d, 16 consecutive t's (hi only)
    {
        const int d = tid & 127, half = tid >> 7;
        ushort8 h0, h1;
#pragma unroll
        for (int j = 0; j < 8; ++j) h0[j] = bfbits(hs[half * 16 + j][d]);
#pragma unroll
        for (int j = 0; j < 8; ++j) h1[j] = bfbits(hs[half * 16 + 8 + j][d]);
        const int b = t0 >> 11;
        const int tloc = t0 & 2047;
        size_t base = ((size_t)(b * 128 + d)) * 2048 + tloc + half * 16;
        *(ushort8*)(HTh + base) = h0;
        *(ushort8*)(HTh + base + 8) = h1;
    }
    // f1 = h@a1, f2 = h@a2 (pre-scaled by log2e)
    {
        const int r = tid & 31, seg = tid >> 5;
        float s1 = 0.f, s2 = 0.f;
#pragma unroll
        for (int i = 0; i < 16; ++i) {
            float hv = hs[r][seg * 16 + i];
            s1 += hv * a[seg * 16 + i];
            s2 += hv * a[128 + seg * 16 + i];
        }
        red[0][r][seg] = s1;
        red[1][r][seg] = s2;
    }
    __syncthreads();
    if (tid < 32) {
        float s1 = 0.f, s2 = 0.f;
#pragma unroll
        for (int g = 0; g < 8; ++g) { s1 += red[0][tid][g]; s2 += red[1][tid][g]; }
        f1l[t0 + tid] = s1 * LOG2E;
        f2l[t0 + tid] = s2 * LOG2E;
    }
}

// ---- kernel 1b: per-batch max of f2l ------------------------------------------
__global__ __launch_bounds__(256) void gat_f2max(const float* __restrict__ f2l,
                                                 float* __restrict__ f2m) {
    const int b = blockIdx.x;
    const int tid = threadIdx.x;
    float m = -3.4e38f;
    for (int j = tid; j < 2048; j += 256) m = fmaxf(m, f2l[b * 2048 + j]);
#pragma unroll
    for (int o = 1; o < 64; o <<= 1) m = fmaxf(m, __shfl_xor(m, o, 64));
    __shared__ float wm_[4];
    if ((tid & 63) == 0) wm_[tid >> 6] = m;
    __syncthreads();
    if (tid == 0) f2m[b] = fmaxf(fmaxf(wm_[0], wm_[1]), fmaxf(wm_[2], wm_[3]));
}

// ---- kernel 2: fused P-gen + softmax-denominator + P@H -------------------------
// 1024 threads = 16 waves: (wm,wn) 2x2 output quadrants x wj 4-way j-split.
__global__ __launch_bounds__(1024) void gat_attn(const unsigned short* __restrict__ HTh,
                                                 const float* __restrict__ f1l,
                                                 const float* __restrict__ f2l,
                                                 const float* __restrict__ f2m,
                                                 float* __restrict__ out) {
    __shared__ float lred[3][2][2][32][64];   // 96 KB partial accumulators (wj=1..3)
    __shared__ float sps[4][2][32];           // partial softmax sums
    const int bid = blockIdx.x;
    const int b = bid & 7;          // batch == XCD for L2 locality
    const int tile = bid >> 3;      // 0..31
    const int tid = threadIdx.x;
    const int lane = tid & 63;
    const int wv = tid >> 6;        // 0..15
    const int wj = wv >> 2;         // 0..3: j-chunk
    const int wm = (wv >> 1) & 1, wn = wv & 1;
    const int l31 = lane & 31;
    const int koff = (lane >> 5) << 3;

    const int rowg = tile * 64 + wm * 32 + l31;
    const float f1m = f1l[b * 2048 + rowg];
    const float tm = f1m + f2m[b];
    const float ml = fmaxf(tm, 0.2f * tm);   // exact row max (lrelu monotonic)

    const int jbase = wj * 512;
    const float* f2b = f2l + b * 2048 + jbase;
    const int c0 = wn * 64;
    const unsigned short* ph0 = HTh + ((size_t)(b * 128 + c0 + l31)) * 2048 + jbase + koff;
    const unsigned short* ph1 = ph0 + 32 * 2048;

    f32x16 ah0 = ZERO16, ah1 = ZERO16;
    float sp = 0.f;

    // register double-buffer prefetch within this wave's 512-j chunk
    float4 fva = *(const float4*)(f2b + koff);
    float4 fvb = *(const float4*)(f2b + koff + 4);
    uint4 vh0 = *(const uint4*)(ph0);
    uint4 vh1 = *(const uint4*)(ph1);

    for (int jl = 0; jl < 512; jl += 16) {
        const int jn = (jl + 16) & 511;   // last iter harmlessly reloads chunk start
        float4 nfa = *(const float4*)(f2b + jn + koff);
        float4 nfb = *(const float4*)(f2b + jn + koff + 4);
        uint4 nh0 = *(const uint4*)(ph0 + jn);
        uint4 nh1 = *(const uint4*)(ph1 + jn);

        float fv[8] = {fva.x, fva.y, fva.z, fva.w, fvb.x, fvb.y, fvb.z, fvb.w};
        short8 af;
#pragma unroll
        for (int q = 0; q < 8; ++q) {
            float t = f1m + fv[q];
            float e = fmaxf(t, 0.2f * t);           // == lrelu(t), alpha=0.2
            float p = __builtin_amdgcn_exp2f(e - ml);
            sp += p;
            af[q] = (short)bfbits(p);
        }
        ah0 = MFMA32(af, __builtin_bit_cast(short8, vh0), ah0);
        ah1 = MFMA32(af, __builtin_bit_cast(short8, vh1), ah1);

        fva = nfa; fvb = nfb;
        vh0 = nh0; vh1 = nh1;
    }

    // partial softmax sum: combine the two koff halves, publish per (wj, wm)
    float spo = __shfl_xor(sp, 32, 64);
    sp += spo;
    if (wn == 0 && lane < 32) sps[wj][wm][l31] = sp;

    // partial accumulators: wj=1..3 publish to LDS
    if (wj > 0) {
#pragma unroll
        for (int r = 0; r < 16; ++r) {
            int crow = (r & 3) + 8 * (r >> 2) + 4 * (lane >> 5);
            lred[wj - 1][wm][wn][crow][l31] = ah0[r];
            lred[wj - 1][wm][wn][crow][32 + l31] = ah1[r];
        }
    }
    __syncthreads();

    if (wj == 0) {
        const size_t obase = ((size_t)b * 2048 + (size_t)tile * 64 + wm * 32) * 128 + c0 + l31;
#pragma unroll
        for (int r = 0; r < 16; ++r) {
            int crow = (r & 3) + 8 * (r >> 2) + 4 * (lane >> 5);
            float s0 = ah0[r] + lred[0][wm][wn][crow][l31]
                     + lred[1][wm][wn][crow][l31] + lred[2][wm][wn][crow][l31];
            float s1 = ah1[r] + lred[0][wm][wn][crow][32 + l31]
                     + lred[1][wm][wn][crow][32 + l31] + lred[2][wm][wn][crow][32 + l31];
            float inv = 1.0f / (sps[0][wm][crow] + sps[1][wm][crow]
                              + sps[2][wm][crow] + sps[3][wm][crow]);
            out[obase + (size_t)crow * 128] = s0 * inv;
            out[obase + (size_t)crow * 128 + 32] = s1 * inv;
        }
    }
}

extern "C" void kernel_launch(void* const* d_in, const int* in_sizes, int n_in,
                              void* d_out, int out_size, void* d_ws, size_t ws_size,
                              hipStream_t stream) {
    const float* x = (const float*)d_in[0];
    const float* W = (const float*)d_in[1];
    const float* a = (const float*)d_in[2];
    float* out = (float*)d_out;

    unsigned short* WTh = (unsigned short*)d_ws;
    unsigned short* WTl = WTh + 128 * 128;
    unsigned short* HTh = WTl + 128 * 128;
    float* f1l = (float*)(HTh + (size_t)8 * 128 * 2048);
    float* f2l = f1l + 16384;
    float* f2m = f2l + 16384;

    gat_wt<<<16, 128, 0, stream>>>(W, WTh, WTl);
    gat_h<<<512, 256, 0, stream>>>(x, WTh, WTl, a, HTh, f1l, f2l);
    gat_f2max<<<8, 256, 0, stream>>>(f2l, f2m);
    gat_attn<<<256, 1024, 0, stream>>>(HTh, f1l, f2l, f2m, out);
}

// Round 3
// 42.422 us; speedup vs baseline: 2.2593x; 1.5273x over previous
//
#include <hip/hip_runtime.h>
#include <hip/hip_bf16.h>

typedef __attribute__((ext_vector_type(8))) short short8;
typedef __attribute__((ext_vector_type(8))) unsigned short ushort8;
typedef __attribute__((ext_vector_type(16))) float f32x16;

#define LOG2E 1.4426950408889634f
#define MFMA32(a, b, c) __builtin_amdgcn_mfma_f32_32x32x16_bf16((a), (b), (c), 0, 0, 0)
#define ZERO16 {0.f,0.f,0.f,0.f,0.f,0.f,0.f,0.f,0.f,0.f,0.f,0.f,0.f,0.f,0.f,0.f}

__device__ __forceinline__ unsigned short bfbits(float f) {
    __hip_bfloat16 h = __float2bfloat16(f);
    return __builtin_bit_cast(unsigned short, h);
}
__device__ __forceinline__ float bf2f(unsigned short u) {
    unsigned v = ((unsigned)u) << 16;
    return __builtin_bit_cast(float, v);
}

// ---- kernel 0: W[k][d] -> WT2[k/16][d][k%16] bf16 hi/lo (MFMA-B tiled) ---------
__global__ __launch_bounds__(256) void gat_wt(const float* __restrict__ W,
                                              unsigned short* __restrict__ WT2h,
                                              unsigned short* __restrict__ WT2l) {
    const int k16 = blockIdx.x;            // 8 tiles of 16 k
    const int d = threadIdx.x >> 1;
    const int klo8 = (threadIdx.x & 1) * 8;
    ushort8 vh, vl;
#pragma unroll
    for (int q = 0; q < 8; ++q) {
        float f = W[(k16 * 16 + klo8 + q) * 128 + d];
        unsigned short hb = bfbits(f);
        vh[q] = hb;
        vl[q] = bfbits(f - bf2f(hb));
    }
    size_t base = (size_t)k16 * 2048 + d * 16 + klo8;
    *(ushort8*)(WT2h + base) = vh;
    *(ushort8*)(WT2l + base) = vl;
}

// ---- kernel 1: h = x@W via MFMA (hi/lo); writes HT2[j/16][d][j%16], f1l, f2l ---
__global__ __launch_bounds__(256) void gat_h(const float* __restrict__ x,
                                             const unsigned short* __restrict__ WT2h,
                                             const unsigned short* __restrict__ WT2l,
                                             const float* __restrict__ a,
                                             unsigned short* __restrict__ HT2h,
                                             float* __restrict__ f1l,
                                             float* __restrict__ f2l) {
    __shared__ unsigned short xs_h[32][132];
    __shared__ unsigned short xs_l[32][132];
    __shared__ float hs[32][130];
    __shared__ float red[2][32][8];
    const int tid = threadIdx.x;
    const int lane = tid & 63;
    const int wv = tid >> 6;          // 4 waves, one 32-col tile each
    const int l31 = lane & 31;
    const int hi = lane >> 5;
    const int t0 = blockIdx.x * 32;   // global row (8*2048 rows total)
    const int c0 = wv * 32;

    // stage x tile coalesced, convert to bf16 hi/lo once
#pragma unroll
    for (int r8 = 0; r8 < 4; ++r8) {
        int row = r8 * 8 + (tid >> 5);
        int c4 = (tid & 31) * 4;
        float4 v = *(const float4*)(x + (size_t)(t0 + row) * 128 + c4);
        float f[4] = {v.x, v.y, v.z, v.w};
#pragma unroll
        for (int q = 0; q < 4; ++q) {
            unsigned short hb = bfbits(f[q]);
            xs_h[row][c4 + q] = hb;
            xs_l[row][c4 + q] = bfbits(f[q] - bf2f(hb));
        }
    }
    __syncthreads();

    f32x16 p0 = ZERO16, p1 = ZERO16, p2 = ZERO16;  // xhi*Whi, xlo*Whi, xhi*Wlo
    const unsigned short* bph = WT2h + (c0 + l31) * 16 + 8 * hi;
    const unsigned short* bpl = WT2l + (c0 + l31) * 16 + 8 * hi;
#pragma unroll
    for (int kk8 = 0; kk8 < 8; ++kk8) {
        short8 ah = *(const short8*)&xs_h[l31][kk8 * 16 + 8 * hi];
        short8 al = *(const short8*)&xs_l[l31][kk8 * 16 + 8 * hi];
        short8 bh = __builtin_bit_cast(short8, *(const ushort8*)(bph + kk8 * 2048));
        short8 bl = __builtin_bit_cast(short8, *(const ushort8*)(bpl + kk8 * 2048));
        p0 = MFMA32(ah, bh, p0);
        p1 = MFMA32(al, bh, p1);
        p2 = MFMA32(ah, bl, p2);
    }
#pragma unroll
    for (int r = 0; r < 16; ++r) {
        int crow = (r & 3) + 8 * (r >> 2) + 4 * hi;
        hs[crow][c0 + l31] = p0[r] + p1[r] + p2[r];
    }
    __syncthreads();
    // HT2 writes: thread owns one d, 16 consecutive j's -> contiguous 32B
    {
        const int d = tid & 127, half = tid >> 7;
        ushort8 h0, h1;
#pragma unroll
        for (int j = 0; j < 8; ++j) h0[j] = bfbits(hs[half * 16 + j][d]);
#pragma unroll
        for (int j = 0; j < 8; ++j) h1[j] = bfbits(hs[half * 16 + 8 + j][d]);
        const int b = t0 >> 11;
        const int tloc = t0 & 2047;
        size_t base = (size_t)b * 262144 + (size_t)(tloc / 16 + half) * 2048 + d * 16;
        *(ushort8*)(HT2h + base) = h0;
        *(ushort8*)(HT2h + base + 8) = h1;
    }
    // f1 = h@a1, f2 = h@a2 (pre-scaled by log2e)
    {
        const int r = tid & 31, seg = tid >> 5;
        float s1 = 0.f, s2 = 0.f;
#pragma unroll
        for (int i = 0; i < 16; ++i) {
            float hv = hs[r][seg * 16 + i];
            s1 += hv * a[seg * 16 + i];
            s2 += hv * a[128 + seg * 16 + i];
        }
        red[0][r][seg] = s1;
        red[1][r][seg] = s2;
    }
    __syncthreads();
    if (tid < 32) {
        float s1 = 0.f, s2 = 0.f;
#pragma unroll
        for (int g = 0; g < 8; ++g) { s1 += red[0][tid][g]; s2 += red[1][tid][g]; }
        f1l[t0 + tid] = s1 * LOG2E;
        f2l[t0 + tid] = s2 * LOG2E;
    }
}

// ---- kernel 1b: per-batch max of f2l ------------------------------------------
__global__ __launch_bounds__(256) void gat_f2max(const float* __restrict__ f2l,
                                                 float* __restrict__ f2m) {
    const int b = blockIdx.x;
    const int tid = threadIdx.x;
    float m = -3.4e38f;
    for (int j = tid; j < 2048; j += 256) m = fmaxf(m, f2l[b * 2048 + j]);
#pragma unroll
    for (int o = 1; o < 64; o <<= 1) m = fmaxf(m, __shfl_xor(m, o, 64));
    __shared__ float wm_[4];
    if ((tid & 63) == 0) wm_[tid >> 6] = m;
    __syncthreads();
    if (tid == 0) f2m[b] = fmaxf(fmaxf(wm_[0], wm_[1]), fmaxf(wm_[2], wm_[3]));
}

// ---- kernel 2: fused P-gen + softmax-denominator + P@H -------------------------
// 512 threads = 8 waves: wn (2 d-halves) x wj (4 j-chunks). Each wave: 64 rows.
__global__ __launch_bounds__(512) void gat_attn(const unsigned short* __restrict__ HT2h,
                                                const float* __restrict__ f1l,
                                                const float* __restrict__ f2l,
                                                const float* __restrict__ f2m,
                                                float* __restrict__ out) {
    __shared__ float lred[3][2][64][64];   // 96 KB partials (wj=1..3)
    __shared__ float sps[4][64];
    const int bid = blockIdx.x;
    const int b = bid & 7;          // batch == XCD for L2 locality
    const int tile = bid >> 3;      // 0..31, 64 rows each
    const int tid = threadIdx.x;
    const int lane = tid & 63;
    const int wv = tid >> 6;        // 0..7
    const int wj = wv >> 1;         // 0..3: j-chunk
    const int wn = wv & 1;          // 0..1: d-half
    const int l31 = lane & 31;
    const int hi = lane >> 5;
    const int koff = hi * 8;

    const float fm = f2m[b];
    const float f1m0 = f1l[b * 2048 + tile * 64 + l31];
    const float f1m1 = f1l[b * 2048 + tile * 64 + 32 + l31];
    const float tm0 = f1m0 + fm, tm1 = f1m1 + fm;
    const float ml0 = fmaxf(tm0, 0.2f * tm0);    // exact row max (lrelu monotonic)
    const float ml1 = fmaxf(tm1, 0.2f * tm1);
    const float A0 = f1m0 - ml0, B0 = 0.2f * f1m0 - ml0;
    const float A1 = f1m1 - ml1, B1 = 0.2f * f1m1 - ml1;

    const int jbase = wj * 512;
    const float* f2b = f2l + b * 2048 + jbase;
    const int c0 = wn * 64;
    // HT2[j/16][d][j%16]: wave's B-fragment load is 1KB contiguous
    const unsigned short* ph = HT2h + (size_t)b * 262144
                             + (size_t)(jbase / 16) * 2048 + (c0 + l31) * 16 + koff;

    f32x16 a00 = ZERO16, a01 = ZERO16, a10 = ZERO16, a11 = ZERO16;
    float sp0 = 0.f, sp1 = 0.f;

    float4 fva = *(const float4*)(f2b + koff);
    float4 fvb = *(const float4*)(f2b + koff + 4);
    uint4 vh0 = *(const uint4*)(ph);
    uint4 vh1 = *(const uint4*)(ph + 512);

    for (int jl = 0; jl < 512; jl += 16) {
        const int jn = (jl + 16) & 511;   // last iter harmlessly reloads chunk start
        float4 nfa = *(const float4*)(f2b + jn + koff);
        float4 nfb = *(const float4*)(f2b + jn + koff + 4);
        uint4 nh0 = *(const uint4*)(ph + (size_t)jn * 128);
        uint4 nh1 = *(const uint4*)(ph + (size_t)jn * 128 + 512);

        float fv[8] = {fva.x, fva.y, fva.z, fva.w, fvb.x, fvb.y, fvb.z, fvb.w};
        short8 af0, af1;
#pragma unroll
        for (int q = 0; q < 8; ++q) {
            float g = 0.2f * fv[q];
            float p0 = __builtin_amdgcn_exp2f(fmaxf(A0 + fv[q], B0 + g));
            float p1 = __builtin_amdgcn_exp2f(fmaxf(A1 + fv[q], B1 + g));
            sp0 += p0; sp1 += p1;
            af0[q] = (short)bfbits(p0);
            af1[q] = (short)bfbits(p1);
        }
        a00 = MFMA32(af0, __builtin_bit_cast(short8, vh0), a00);
        a01 = MFMA32(af0, __builtin_bit_cast(short8, vh1), a01);
        a10 = MFMA32(af1, __builtin_bit_cast(short8, vh0), a10);
        a11 = MFMA32(af1, __builtin_bit_cast(short8, vh1), a11);

        fva = nfa; fvb = nfb;
        vh0 = nh0; vh1 = nh1;
    }

    sp0 += __shfl_xor(sp0, 32, 64);
    sp1 += __shfl_xor(sp1, 32, 64);
    if (wn == 0 && lane < 32) { sps[wj][l31] = sp0; sps[wj][32 + l31] = sp1; }

    if (wj > 0) {
#pragma unroll
        for (int r = 0; r < 16; ++r) {
            int crow = (r & 3) + 8 * (r >> 2) + 4 * hi;
            lred[wj - 1][wn][crow][l31] = a00[r];
            lred[wj - 1][wn][crow][32 + l31] = a01[r];
            lred[wj - 1][wn][32 + crow][l31] = a10[r];
            lred[wj - 1][wn][32 + crow][32 + l31] = a11[r];
        }
    }
    __syncthreads();

    if (wj == 0) {
        const size_t obase = ((size_t)b * 2048 + (size_t)tile * 64) * 128 + c0 + l31;
#pragma unroll
        for (int r = 0; r < 16; ++r) {
            int crow = (r & 3) + 8 * (r >> 2) + 4 * hi;
            float s00 = a00[r] + lred[0][wn][crow][l31]
                      + lred[1][wn][crow][l31] + lred[2][wn][crow][l31];
            float s01 = a01[r] + lred[0][wn][crow][32 + l31]
                      + lred[1][wn][crow][32 + l31] + lred[2][wn][crow][32 + l31];
            float s10 = a10[r] + lred[0][wn][32 + crow][l31]
                      + lred[1][wn][32 + crow][l31] + lred[2][wn][32 + crow][l31];
            float s11 = a11[r] + lred[0][wn][32 + crow][32 + l31]
                      + lred[1][wn][32 + crow][32 + l31] + lred[2][wn][32 + crow][32 + l31];
            float inv0 = 1.0f / (sps[0][crow] + sps[1][crow] + sps[2][crow] + sps[3][crow]);
            float inv1 = 1.0f / (sps[0][32 + crow] + sps[1][32 + crow]
                               + sps[2][32 + crow] + sps[3][32 + crow]);
            out[obase + (size_t)crow * 128] = s00 * inv0;
            out[obase + (size_t)crow * 128 + 32] = s01 * inv0;
            out[obase + (size_t)(32 + crow) * 128] = s10 * inv1;
            out[obase + (size_t)(32 + crow) * 128 + 32] = s11 * inv1;
        }
    }
}

extern "C" void kernel_launch(void* const* d_in, const int* in_sizes, int n_in,
                              void* d_out, int out_size, void* d_ws, size_t ws_size,
                              hipStream_t stream) {
    const float* x = (const float*)d_in[0];
    const float* W = (const float*)d_in[1];
    const float* a = (const float*)d_in[2];
    float* out = (float*)d_out;

    unsigned short* WT2h = (unsigned short*)d_ws;
    unsigned short* WT2l = WT2h + 128 * 128;
    unsigned short* HT2h = WT2l + 128 * 128;
    float* f1l = (float*)(HT2h + (size_t)8 * 128 * 2048);
    float* f2l = f1l + 16384;
    float* f2m = f2l + 16384;

    gat_wt<<<8, 256, 0, stream>>>(W, WT2h, WT2l);
    gat_h<<<512, 256, 0, stream>>>(x, WT2h, WT2l, a, HT2h, f1l, f2l);
    gat_f2max<<<8, 256, 0, stream>>>(f2l, f2m);
    gat_attn<<<256, 512, 0, stream>>>(HT2h, f1l, f2l, f2m, out);
}

// Round 4
// 40.160 us; speedup vs baseline: 2.3866x; 1.0563x over previous
//
#include <hip/hip_runtime.h>
#include <hip/hip_bf16.h>

typedef __attribute__((ext_vector_type(8))) short short8;
typedef __attribute__((ext_vector_type(8))) unsigned short ushort8;
typedef __attribute__((ext_vector_type(16))) float f32x16;

#define LOG2E 1.4426950408889634f
#define MFMA32(a, b, c) __builtin_amdgcn_mfma_f32_32x32x16_bf16((a), (b), (c), 0, 0, 0)
#define ZERO16 {0.f,0.f,0.f,0.f,0.f,0.f,0.f,0.f,0.f,0.f,0.f,0.f,0.f,0.f,0.f,0.f}

__device__ __forceinline__ unsigned short bfbits(float f) {
    __hip_bfloat16 h = __float2bfloat16(f);
    return __builtin_bit_cast(unsigned short, h);
}
__device__ __forceinline__ float bf2f(unsigned short u) {
    unsigned v = ((unsigned)u) << 16;
    return __builtin_bit_cast(float, v);
}

// ---- kernel 0: W[k][d] -> WT2[k/16][d][k%16] bf16 hi/lo; init f2m keys ---------
__global__ __launch_bounds__(256) void gat_wt(const float* __restrict__ W,
                                              unsigned short* __restrict__ WT2h,
                                              unsigned short* __restrict__ WT2l,
                                              unsigned int* __restrict__ f2mk) {
    if (blockIdx.x == 0 && threadIdx.x < 8) f2mk[threadIdx.x] = 0u;
    const int k16 = blockIdx.x;            // 8 tiles of 16 k
    const int d = threadIdx.x >> 1;
    const int klo8 = (threadIdx.x & 1) * 8;
    ushort8 vh, vl;
#pragma unroll
    for (int q = 0; q < 8; ++q) {
        float f = W[(k16 * 16 + klo8 + q) * 128 + d];
        unsigned short hb = bfbits(f);
        vh[q] = hb;
        vl[q] = bfbits(f - bf2f(hb));
    }
    size_t base = (size_t)k16 * 2048 + d * 16 + klo8;
    *(ushort8*)(WT2h + base) = vh;
    *(ushort8*)(WT2l + base) = vl;
}

// ---- kernel 1: h = x@W via MFMA (hi/lo); writes HT2[j/16][d][j%16], f1l, f2l,
//                and per-batch f2 max via atomicMax on sign-flipped uint key ----
__global__ __launch_bounds__(256) void gat_h(const float* __restrict__ x,
                                             const unsigned short* __restrict__ WT2h,
                                             const unsigned short* __restrict__ WT2l,
                                             const float* __restrict__ a,
                                             unsigned short* __restrict__ HT2h,
                                             float* __restrict__ f1l,
                                             float* __restrict__ f2l,
                                             unsigned int* __restrict__ f2mk) {
    __shared__ unsigned short xs_h[32][132];
    __shared__ unsigned short xs_l[32][132];
    __shared__ float hs[32][130];
    __shared__ float red[2][32][8];
    const int tid = threadIdx.x;
    const int lane = tid & 63;
    const int wv = tid >> 6;          // 4 waves, one 32-col tile each
    const int l31 = lane & 31;
    const int hi = lane >> 5;
    const int t0 = blockIdx.x * 32;   // global row (8*2048 rows total)
    const int c0 = wv * 32;

    // stage x tile coalesced, convert to bf16 hi/lo once
#pragma unroll
    for (int r8 = 0; r8 < 4; ++r8) {
        int row = r8 * 8 + (tid >> 5);
        int c4 = (tid & 31) * 4;
        float4 v = *(const float4*)(x + (size_t)(t0 + row) * 128 + c4);
        float f[4] = {v.x, v.y, v.z, v.w};
#pragma unroll
        for (int q = 0; q < 4; ++q) {
            unsigned short hb = bfbits(f[q]);
            xs_h[row][c4 + q] = hb;
            xs_l[row][c4 + q] = bfbits(f[q] - bf2f(hb));
        }
    }
    __syncthreads();

    f32x16 p0 = ZERO16, p1 = ZERO16, p2 = ZERO16;  // xhi*Whi, xlo*Whi, xhi*Wlo
    const unsigned short* bph = WT2h + (c0 + l31) * 16 + 8 * hi;
    const unsigned short* bpl = WT2l + (c0 + l31) * 16 + 8 * hi;
#pragma unroll
    for (int kk8 = 0; kk8 < 8; ++kk8) {
        short8 ah = *(const short8*)&xs_h[l31][kk8 * 16 + 8 * hi];
        short8 al = *(const short8*)&xs_l[l31][kk8 * 16 + 8 * hi];
        short8 bh = __builtin_bit_cast(short8, *(const ushort8*)(bph + kk8 * 2048));
        short8 bl = __builtin_bit_cast(short8, *(const ushort8*)(bpl + kk8 * 2048));
        p0 = MFMA32(ah, bh, p0);
        p1 = MFMA32(al, bh, p1);
        p2 = MFMA32(ah, bl, p2);
    }
#pragma unroll
    for (int r = 0; r < 16; ++r) {
        int crow = (r & 3) + 8 * (r >> 2) + 4 * hi;
        hs[crow][c0 + l31] = p0[r] + p1[r] + p2[r];
    }
    __syncthreads();
    // HT2 writes: thread owns one d, 16 consecutive j's -> contiguous 32B
    {
        const int d = tid & 127, half = tid >> 7;
        ushort8 h0, h1;
#pragma unroll
        for (int j = 0; j < 8; ++j) h0[j] = bfbits(hs[half * 16 + j][d]);
#pragma unroll
        for (int j = 0; j < 8; ++j) h1[j] = bfbits(hs[half * 16 + 8 + j][d]);
        const int b = t0 >> 11;
        const int tloc = t0 & 2047;
        size_t base = (size_t)b * 262144 + (size_t)(tloc / 16 + half) * 2048 + d * 16;
        *(ushort8*)(HT2h + base) = h0;
        *(ushort8*)(HT2h + base + 8) = h1;
    }
    // f1 = h@a1, f2 = h@a2 (pre-scaled by log2e)
    {
        const int r = tid & 31, seg = tid >> 5;
        float s1 = 0.f, s2 = 0.f;
#pragma unroll
        for (int i = 0; i < 16; ++i) {
            float hv = hs[r][seg * 16 + i];
            s1 += hv * a[seg * 16 + i];
            s2 += hv * a[128 + seg * 16 + i];
        }
        red[0][r][seg] = s1;
        red[1][r][seg] = s2;
    }
    __syncthreads();
    if (tid < 32) {
        float s1 = 0.f, s2 = 0.f;
#pragma unroll
        for (int g = 0; g < 8; ++g) { s1 += red[0][tid][g]; s2 += red[1][tid][g]; }
        f1l[t0 + tid] = s1 * LOG2E;
        float f2v = s2 * LOG2E;
        f2l[t0 + tid] = f2v;
        // block-level f2 max -> one atomicMax per block (sign-flipped uint key)
        float m = f2v;
#pragma unroll
        for (int o = 1; o < 32; o <<= 1) m = fmaxf(m, __shfl_xor(m, o, 32));
        if (tid == 0) {
            unsigned int bits = __builtin_bit_cast(unsigned int, m);
            unsigned int key = (bits & 0x80000000u) ? ~bits : (bits | 0x80000000u);
            atomicMax(f2mk + (t0 >> 11), key);
        }
    }
}

// ---- kernel 2: fused P-gen + softmax-denominator + P@H -------------------------
// 512 threads = 8 waves, each wave: 64 rows x ALL 128 d x one 256-j chunk.
// P computed exactly once; cross-wave combine via 3-stage LDS tree.
__global__ __launch_bounds__(512, 2) void gat_attn(const unsigned short* __restrict__ HT2h,
                                                   const float* __restrict__ f1l,
                                                   const float* __restrict__ f2l,
                                                   const unsigned int* __restrict__ f2mk,
                                                   float* __restrict__ out) {
    __shared__ float lred[4][64][132];   // 135 KB partial regions
    __shared__ float sps[8][64];
    __shared__ float sinv[64];
    const int bid = blockIdx.x;
    const int b = bid & 7;          // batch == XCD for L2 locality
    const int tile = bid >> 3;      // 0..31, 64 rows each
    const int tid = threadIdx.x;
    const int lane = tid & 63;
    const int wv = tid >> 6;        // 0..7 = j-chunk
    const int l31 = lane & 31;
    const int hi = lane >> 5;
    const int koff = hi * 8;

    const unsigned int kk = f2mk[b];
    const unsigned int mbits = (kk & 0x80000000u) ? (kk & 0x7fffffffu) : ~kk;
    const float fm = __builtin_bit_cast(float, mbits);

    const int rowg = b * 2048 + tile * 64 + l31;
    const float f1m0 = f1l[rowg];
    const float f1m1 = f1l[rowg + 32];
    const float tm0 = f1m0 + fm, tm1 = f1m1 + fm;
    const float ml0 = fmaxf(tm0, 0.2f * tm0);    // exact row max (lrelu monotonic)
    const float ml1 = fmaxf(tm1, 0.2f * tm1);
    const float A0 = f1m0 - ml0, B0 = 0.2f * f1m0 - ml0;
    const float A1 = f1m1 - ml1, B1 = 0.2f * f1m1 - ml1;

    const int jbase = wv * 256;
    const float* f2b = f2l + b * 2048 + jbase;
    const unsigned short* ph = HT2h + (size_t)b * 262144
                             + (size_t)(jbase >> 4) * 2048 + l31 * 16 + koff;

    f32x16 acc[2][4] = {{ZERO16, ZERO16, ZERO16, ZERO16},
                        {ZERO16, ZERO16, ZERO16, ZERO16}};
    float sp0 = 0.f, sp1 = 0.f;

    uint4 vh0 = *(const uint4*)(ph);
    uint4 vh1 = *(const uint4*)(ph + 512);
    uint4 vh2 = *(const uint4*)(ph + 1024);
    uint4 vh3 = *(const uint4*)(ph + 1536);

    for (int it = 0; it < 16; ++it) {
        const unsigned short* pn = ph + (size_t)((it + 1) & 15) * 2048;
        uint4 nh0 = *(const uint4*)(pn);
        uint4 nh1 = *(const uint4*)(pn + 512);
        uint4 nh2 = *(const uint4*)(pn + 1024);
        uint4 nh3 = *(const uint4*)(pn + 1536);
        float4 fva = *(const float4*)(f2b + it * 16 + koff);
        float4 fvb = *(const float4*)(f2b + it * 16 + koff + 4);

        float fv[8] = {fva.x, fva.y, fva.z, fva.w, fvb.x, fvb.y, fvb.z, fvb.w};
        short8 af0, af1;
#pragma unroll
        for (int q = 0; q < 8; ++q) {
            float g = 0.2f * fv[q];
            float p0 = __builtin_amdgcn_exp2f(fmaxf(A0 + fv[q], B0 + g));
            float p1 = __builtin_amdgcn_exp2f(fmaxf(A1 + fv[q], B1 + g));
            sp0 += p0; sp1 += p1;
            af0[q] = (short)bfbits(p0);
            af1[q] = (short)bfbits(p1);
        }
        acc[0][0] = MFMA32(af0, __builtin_bit_cast(short8, vh0), acc[0][0]);
        acc[0][1] = MFMA32(af0, __builtin_bit_cast(short8, vh1), acc[0][1]);
        acc[0][2] = MFMA32(af0, __builtin_bit_cast(short8, vh2), acc[0][2]);
        acc[0][3] = MFMA32(af0, __builtin_bit_cast(short8, vh3), acc[0][3]);
        acc[1][0] = MFMA32(af1, __builtin_bit_cast(short8, vh0), acc[1][0]);
        acc[1][1] = MFMA32(af1, __builtin_bit_cast(short8, vh1), acc[1][1]);
        acc[1][2] = MFMA32(af1, __builtin_bit_cast(short8, vh2), acc[1][2]);
        acc[1][3] = MFMA32(af1, __builtin_bit_cast(short8, vh3), acc[1][3]);

        vh0 = nh0; vh1 = nh1; vh2 = nh2; vh3 = nh3;
    }

    // per-row softmax partial sums (combine hi halves)
    sp0 += __shfl_xor(sp0, 32, 64);
    sp1 += __shfl_xor(sp1, 32, 64);
    if (lane < 32) { sps[wv][l31] = sp0; sps[wv][32 + l31] = sp1; }

    // ---- 3-stage cross-wave reduction tree ----
    if (wv >= 4) {
#pragma unroll
        for (int r = 0; r < 16; ++r) {
            int crow = (r & 3) + 8 * (r >> 2) + 4 * hi;
#pragma unroll
            for (int s = 0; s < 2; ++s)
#pragma unroll
                for (int c = 0; c < 4; ++c)
                    lred[wv - 4][s * 32 + crow][c * 32 + l31] = acc[s][c][r];
        }
    }
    __syncthreads();
    if (wv < 4) {
#pragma unroll
        for (int r = 0; r < 16; ++r) {
            int crow = (r & 3) + 8 * (r >> 2) + 4 * hi;
#pragma unroll
            for (int s = 0; s < 2; ++s)
#pragma unroll
                for (int c = 0; c < 4; ++c)
                    acc[s][c][r] += lred[wv][s * 32 + crow][c * 32 + l31];
        }
    } else if (wv == 4) {
        float tot = 0.f;
#pragma unroll
        for (int w = 0; w < 8; ++w) tot += sps[w][lane];
        sinv[lane] = 1.0f / tot;
    }
    __syncthreads();
    if (wv == 2 || wv == 3) {
#pragma unroll
        for (int r = 0; r < 16; ++r) {
            int crow = (r & 3) + 8 * (r >> 2) + 4 * hi;
#pragma unroll
            for (int s = 0; s < 2; ++s)
#pragma unroll
                for (int c = 0; c < 4; ++c)
                    lred[wv - 2][s * 32 + crow][c * 32 + l31] = acc[s][c][r];
        }
    }
    __syncthreads();
    if (wv < 2) {
#pragma unroll
        for (int r = 0; r < 16; ++r) {
            int crow = (r & 3) + 8 * (r >> 2) + 4 * hi;
#pragma unroll
            for (int s = 0; s < 2; ++s)
#pragma unroll
                for (int c = 0; c < 4; ++c)
                    acc[s][c][r] += lred[wv][s * 32 + crow][c * 32 + l31];
        }
    }
    __syncthreads();
    if (wv == 1) {
#pragma unroll
        for (int r = 0; r < 16; ++r) {
            int crow = (r & 3) + 8 * (r >> 2) + 4 * hi;
#pragma unroll
            for (int s = 0; s < 2; ++s)
#pragma unroll
                for (int c = 0; c < 4; ++c)
                    lred[0][s * 32 + crow][c * 32 + l31] = acc[s][c][r];
        }
    }
    __syncthreads();
    if (wv == 0) {
        const size_t obase = ((size_t)b * 2048 + (size_t)tile * 64) * 128;
#pragma unroll
        for (int r = 0; r < 16; ++r) {
            int crow = (r & 3) + 8 * (r >> 2) + 4 * hi;
#pragma unroll
            for (int s = 0; s < 2; ++s) {
                int row = s * 32 + crow;
                float iv = sinv[row];
#pragma unroll
                for (int c = 0; c < 4; ++c) {
                    float v = acc[s][c][r] + lred[0][row][c * 32 + l31];
                    out[obase + (size_t)row * 128 + c * 32 + l31] = v * iv;
                }
            }
        }
    }
}

extern "C" void kernel_launch(void* const* d_in, const int* in_sizes, int n_in,
                              void* d_out, int out_size, void* d_ws, size_t ws_size,
                              hipStream_t stream) {
    const float* x = (const float*)d_in[0];
    const float* W = (const float*)d_in[1];
    const float* a = (const float*)d_in[2];
    float* out = (float*)d_out;

    unsigned short* WT2h = (unsigned short*)d_ws;
    unsigned short* WT2l = WT2h + 128 * 128;
    unsigned short* HT2h = WT2l + 128 * 128;
    float* f1l = (float*)(HT2h + (size_t)8 * 128 * 2048);
    float* f2l = f1l + 16384;
    unsigned int* f2mk = (unsigned int*)(f2l + 16384);

    gat_wt<<<8, 256, 0, stream>>>(W, WT2h, WT2l, f2mk);
    gat_h<<<512, 256, 0, stream>>>(x, WT2h, WT2l, a, HT2h, f1l, f2l, f2mk);
    gat_attn<<<256, 512, 0, stream>>>(HT2h, f1l, f2l, f2mk, out);
}

// Round 5
// 38.893 us; speedup vs baseline: 2.4643x; 1.0326x over previous
//
#include <hip/hip_runtime.h>
#include <hip/hip_bf16.h>

typedef __attribute__((ext_vector_type(8))) short short8;
typedef __attribute__((ext_vector_type(8))) unsigned short ushort8;
typedef __attribute__((ext_vector_type(16))) float f32x16;

#define LOG2E 1.4426950408889634f
#define MFMA32(a, b, c) __builtin_amdgcn_mfma_f32_32x32x16_bf16((a), (b), (c), 0, 0, 0)
#define ZERO16 {0.f,0.f,0.f,0.f,0.f,0.f,0.f,0.f,0.f,0.f,0.f,0.f,0.f,0.f,0.f,0.f}

__device__ __forceinline__ unsigned short bfbits(float f) {
    __hip_bfloat16 h = __float2bfloat16(f);
    return __builtin_bit_cast(unsigned short, h);
}
__device__ __forceinline__ float bf2f(unsigned short u) {
    unsigned v = ((unsigned)u) << 16;
    return __builtin_bit_cast(float, v);
}

// ---- kernel 0: W[k][d] -> WT2[k/16][d][k%16] bf16 hi/lo; init f2m keys ---------
__global__ __launch_bounds__(256) void gat_wt(const float* __restrict__ W,
                                              unsigned short* __restrict__ WT2h,
                                              unsigned short* __restrict__ WT2l,
                                              unsigned int* __restrict__ f2mk) {
    if (blockIdx.x == 0 && threadIdx.x < 8) f2mk[threadIdx.x] = 0u;
    const int k16 = blockIdx.x;            // 8 tiles of 16 k
    const int d = threadIdx.x >> 1;
    const int klo8 = (threadIdx.x & 1) * 8;
    ushort8 vh, vl;
#pragma unroll
    for (int q = 0; q < 8; ++q) {
        float f = W[(k16 * 16 + klo8 + q) * 128 + d];
        unsigned short hb = bfbits(f);
        vh[q] = hb;
        vl[q] = bfbits(f - bf2f(hb));
    }
    size_t base = (size_t)k16 * 2048 + d * 16 + klo8;
    *(ushort8*)(WT2h + base) = vh;
    *(ushort8*)(WT2l + base) = vl;
}

// ---- kernel 1: h = x@W via MFMA (hi/lo); writes HT2[j/16][d][j%16], f1l, f2l,
//                and per-batch f2 max via atomicMax on sign-flipped uint key ----
__global__ __launch_bounds__(256) void gat_h(const float* __restrict__ x,
                                             const unsigned short* __restrict__ WT2h,
                                             const unsigned short* __restrict__ WT2l,
                                             const float* __restrict__ a,
                                             unsigned short* __restrict__ HT2h,
                                             float* __restrict__ f1l,
                                             float* __restrict__ f2l,
                                             unsigned int* __restrict__ f2mk) {
    __shared__ unsigned short xs_h[32][132];
    __shared__ unsigned short xs_l[32][132];
    __shared__ float hs[32][130];
    __shared__ float red[2][32][8];
    const int tid = threadIdx.x;
    const int lane = tid & 63;
    const int wv = tid >> 6;          // 4 waves, one 32-col tile each
    const int l31 = lane & 31;
    const int hi = lane >> 5;
    const int t0 = blockIdx.x * 32;   // global row (8*2048 rows total)
    const int c0 = wv * 32;

    // stage x tile coalesced, convert to bf16 hi/lo once
#pragma unroll
    for (int r8 = 0; r8 < 4; ++r8) {
        int row = r8 * 8 + (tid >> 5);
        int c4 = (tid & 31) * 4;
        float4 v = *(const float4*)(x + (size_t)(t0 + row) * 128 + c4);
        float f[4] = {v.x, v.y, v.z, v.w};
#pragma unroll
        for (int q = 0; q < 4; ++q) {
            unsigned short hb = bfbits(f[q]);
            xs_h[row][c4 + q] = hb;
            xs_l[row][c4 + q] = bfbits(f[q] - bf2f(hb));
        }
    }
    __syncthreads();

    f32x16 p0 = ZERO16, p1 = ZERO16, p2 = ZERO16;  // xhi*Whi, xlo*Whi, xhi*Wlo
    const unsigned short* bph = WT2h + (c0 + l31) * 16 + 8 * hi;
    const unsigned short* bpl = WT2l + (c0 + l31) * 16 + 8 * hi;
#pragma unroll
    for (int kk8 = 0; kk8 < 8; ++kk8) {
        short8 ah = *(const short8*)&xs_h[l31][kk8 * 16 + 8 * hi];
        short8 al = *(const short8*)&xs_l[l31][kk8 * 16 + 8 * hi];
        short8 bh = __builtin_bit_cast(short8, *(const ushort8*)(bph + kk8 * 2048));
        short8 bl = __builtin_bit_cast(short8, *(const ushort8*)(bpl + kk8 * 2048));
        p0 = MFMA32(ah, bh, p0);
        p1 = MFMA32(al, bh, p1);
        p2 = MFMA32(ah, bl, p2);
    }
#pragma unroll
    for (int r = 0; r < 16; ++r) {
        int crow = (r & 3) + 8 * (r >> 2) + 4 * hi;
        hs[crow][c0 + l31] = p0[r] + p1[r] + p2[r];
    }
    __syncthreads();
    // HT2 writes: thread owns one d, 16 consecutive j's -> contiguous 32B
    {
        const int d = tid & 127, half = tid >> 7;
        ushort8 h0, h1;
#pragma unroll
        for (int j = 0; j < 8; ++j) h0[j] = bfbits(hs[half * 16 + j][d]);
#pragma unroll
        for (int j = 0; j < 8; ++j) h1[j] = bfbits(hs[half * 16 + 8 + j][d]);
        const int b = t0 >> 11;
        const int tloc = t0 & 2047;
        size_t base = (size_t)b * 262144 + (size_t)(tloc / 16 + half) * 2048 + d * 16;
        *(ushort8*)(HT2h + base) = h0;
        *(ushort8*)(HT2h + base + 8) = h1;
    }
    // f1 = h@a1, f2 = h@a2 (pre-scaled by log2e)
    {
        const int r = tid & 31, seg = tid >> 5;
        float s1 = 0.f, s2 = 0.f;
#pragma unroll
        for (int i = 0; i < 16; ++i) {
            float hv = hs[r][seg * 16 + i];
            s1 += hv * a[seg * 16 + i];
            s2 += hv * a[128 + seg * 16 + i];
        }
        red[0][r][seg] = s1;
        red[1][r][seg] = s2;
    }
    __syncthreads();
    if (tid < 32) {
        float s1 = 0.f, s2 = 0.f;
#pragma unroll
        for (int g = 0; g < 8; ++g) { s1 += red[0][tid][g]; s2 += red[1][tid][g]; }
        f1l[t0 + tid] = s1 * LOG2E;
        float f2v = s2 * LOG2E;
        f2l[t0 + tid] = f2v;
        // block-level f2 max -> one atomicMax per block (sign-flipped uint key)
        float m = f2v;
#pragma unroll
        for (int o = 1; o < 32; o <<= 1) m = fmaxf(m, __shfl_xor(m, o, 32));
        if (tid == 0) {
            unsigned int bits = __builtin_bit_cast(unsigned int, m);
            unsigned int key = (bits & 0x80000000u) ? ~bits : (bits | 0x80000000u);
            atomicMax(f2mk + (t0 >> 11), key);
        }
    }
}

// ---- helper: generate af fragments + accumulate softmax partials ---------------
__device__ __forceinline__ void gen_af(float4 fa, float4 fb,
                                       float A0, float B0, float A1, float B1,
                                       float& sp0, float& sp1,
                                       short8& af0, short8& af1) {
    float fv[8] = {fa.x, fa.y, fa.z, fa.w, fb.x, fb.y, fb.z, fb.w};
#pragma unroll
    for (int q = 0; q < 8; ++q) {
        float g = 0.2f * fv[q];
        float p0 = __builtin_amdgcn_exp2f(fmaxf(A0 + fv[q], B0 + g));
        float p1 = __builtin_amdgcn_exp2f(fmaxf(A1 + fv[q], B1 + g));
        sp0 += p0; sp1 += p1;
        af0[q] = (short)bfbits(p0);
        af1[q] = (short)bfbits(p1);
    }
}

// ---- kernel 2: fused P-gen + softmax-denominator + P@H -------------------------
// 512 threads = 8 waves, each wave: 64 rows x ALL 128 d x one 256-j chunk.
// f2 staged in LDS (lgkmcnt path); H prefetch depth-2 via named X/Y buffer sets
// (vmcnt path) so neither wait drains the other.
__global__ __launch_bounds__(512, 2) void gat_attn(const unsigned short* __restrict__ HT2h,
                                                   const float* __restrict__ f1l,
                                                   const float* __restrict__ f2l,
                                                   const unsigned int* __restrict__ f2mk,
                                                   float* __restrict__ out) {
    __shared__ float lred[4][64][128];   // 128 KB partial regions
    __shared__ float f2s[2048];          // 8 KB: this batch's f2 (pre-scaled)
    __shared__ float sps[8][64];
    __shared__ float sinv[64];
    const int bid = blockIdx.x;
    const int b = bid & 7;          // batch == XCD for L2 locality
    const int tile = bid >> 3;      // 0..31, 64 rows each
    const int tid = threadIdx.x;
    const int lane = tid & 63;
    const int wv = tid >> 6;        // 0..7 = j-chunk
    const int l31 = lane & 31;
    const int hi = lane >> 5;
    const int koff = hi * 8;

    // stage f2 batch slice into LDS (one coalesced burst)
    *(float4*)(f2s + tid * 4) = *(const float4*)(f2l + b * 2048 + tid * 4);

    const unsigned int kk = f2mk[b];
    const unsigned int mbits = (kk & 0x80000000u) ? (kk & 0x7fffffffu) : ~kk;
    const float fm = __builtin_bit_cast(float, mbits);

    const int rowg = b * 2048 + tile * 64 + l31;
    const float f1m0 = f1l[rowg];
    const float f1m1 = f1l[rowg + 32];
    const float tm0 = f1m0 + fm, tm1 = f1m1 + fm;
    const float ml0 = fmaxf(tm0, 0.2f * tm0);    // exact row max (lrelu monotonic)
    const float ml1 = fmaxf(tm1, 0.2f * tm1);
    const float A0 = f1m0 - ml0, B0 = 0.2f * f1m0 - ml0;
    const float A1 = f1m1 - ml1, B1 = 0.2f * f1m1 - ml1;

    const int jloc = wv * 256;
    const unsigned short* phg = HT2h + (size_t)b * 262144
                              + (size_t)(jloc >> 4) * 2048 + l31 * 16 + koff;

    f32x16 acc[2][4] = {{ZERO16, ZERO16, ZERO16, ZERO16},
                        {ZERO16, ZERO16, ZERO16, ZERO16}};
    float sp0 = 0.f, sp1 = 0.f;

    // depth-2 prefetch: X = group 0, Y = group 1
    uint4 X0 = *(const uint4*)(phg);
    uint4 X1 = *(const uint4*)(phg + 512);
    uint4 X2 = *(const uint4*)(phg + 1024);
    uint4 X3 = *(const uint4*)(phg + 1536);
    uint4 Y0 = *(const uint4*)(phg + 2048);
    uint4 Y1 = *(const uint4*)(phg + 2048 + 512);
    uint4 Y2 = *(const uint4*)(phg + 2048 + 1024);
    uint4 Y3 = *(const uint4*)(phg + 2048 + 1536);

    __syncthreads();   // f2s ready

    // f2 register prefetch for iteration 0
    float4 fA0 = *(const float4*)(f2s + jloc + koff);
    float4 fA1 = *(const float4*)(f2s + jloc + koff + 4);

    for (int it2 = 0; it2 < 8; ++it2) {
        const int itE = it2 * 2, itO = it2 * 2 + 1;
        // ---- even iteration: consume X, f2 regs fA ----
        short8 af0, af1;
        gen_af(fA0, fA1, A0, B0, A1, B1, sp0, sp1, af0, af1);
        // prefetch odd-iteration f2 (lgkmcnt; hides under MFMA)
        float4 fB0 = *(const float4*)(f2s + jloc + itO * 16 + koff);
        float4 fB1 = *(const float4*)(f2s + jloc + itO * 16 + koff + 4);
        acc[0][0] = MFMA32(af0, __builtin_bit_cast(short8, X0), acc[0][0]);
        acc[0][1] = MFMA32(af0, __builtin_bit_cast(short8, X1), acc[0][1]);
        acc[0][2] = MFMA32(af0, __builtin_bit_cast(short8, X2), acc[0][2]);
        acc[0][3] = MFMA32(af0, __builtin_bit_cast(short8, X3), acc[0][3]);
        acc[1][0] = MFMA32(af1, __builtin_bit_cast(short8, X0), acc[1][0]);
        acc[1][1] = MFMA32(af1, __builtin_bit_cast(short8, X1), acc[1][1]);
        acc[1][2] = MFMA32(af1, __builtin_bit_cast(short8, X2), acc[1][2]);
        acc[1][3] = MFMA32(af1, __builtin_bit_cast(short8, X3), acc[1][3]);
        // issue group(itE+2) -> X (wrap harmlessly at the end)
        {
            const unsigned short* pn = phg + (size_t)((itE + 2) & 15) * 2048;
            X0 = *(const uint4*)(pn);
            X1 = *(const uint4*)(pn + 512);
            X2 = *(const uint4*)(pn + 1024);
            X3 = *(const uint4*)(pn + 1536);
        }
        // ---- odd iteration: consume Y, f2 regs fB ----
        short8 bf0, bf1;
        gen_af(fB0, fB1, A0, B0, A1, B1, sp0, sp1, bf0, bf1);
        // prefetch next-even f2
        {
            const int itN = (itO + 1) & 15;
            fA0 = *(const float4*)(f2s + jloc + itN * 16 + koff);
            fA1 = *(const float4*)(f2s + jloc + itN * 16 + koff + 4);
        }
        acc[0][0] = MFMA32(bf0, __builtin_bit_cast(short8, Y0), acc[0][0]);
        acc[0][1] = MFMA32(bf0, __builtin_bit_cast(short8, Y1), acc[0][1]);
        acc[0][2] = MFMA32(bf0, __builtin_bit_cast(short8, Y2), acc[0][2]);
        acc[0][3] = MFMA32(bf0, __builtin_bit_cast(short8, Y3), acc[0][3]);
        acc[1][0] = MFMA32(bf1, __builtin_bit_cast(short8, Y0), acc[1][0]);
        acc[1][1] = MFMA32(bf1, __builtin_bit_cast(short8, Y1), acc[1][1]);
        acc[1][2] = MFMA32(bf1, __builtin_bit_cast(short8, Y2), acc[1][2]);
        acc[1][3] = MFMA32(bf1, __builtin_bit_cast(short8, Y3), acc[1][3]);
        // issue group(itO+2) -> Y (wrap harmlessly)
        {
            const unsigned short* pn = phg + (size_t)((itO + 2) & 15) * 2048;
            Y0 = *(const uint4*)(pn);
            Y1 = *(const uint4*)(pn + 512);
            Y2 = *(const uint4*)(pn + 1024);
            Y3 = *(const uint4*)(pn + 1536);
        }
    }

    // per-row softmax partial sums (combine hi halves)
    sp0 += __shfl_xor(sp0, 32, 64);
    sp1 += __shfl_xor(sp1, 32, 64);
    if (lane < 32) { sps[wv][l31] = sp0; sps[wv][32 + l31] = sp1; }

    // ---- 3-stage cross-wave reduction tree ----
    if (wv >= 4) {
#pragma unroll
        for (int r = 0; r < 16; ++r) {
            int crow = (r & 3) + 8 * (r >> 2) + 4 * hi;
#pragma unroll
            for (int s = 0; s < 2; ++s)
#pragma unroll
                for (int c = 0; c < 4; ++c)
                    lred[wv - 4][s * 32 + crow][c * 32 + l31] = acc[s][c][r];
        }
    }
    __syncthreads();
    if (wv < 4) {
#pragma unroll
        for (int r = 0; r < 16; ++r) {
            int crow = (r & 3) + 8 * (r >> 2) + 4 * hi;
#pragma unroll
            for (int s = 0; s < 2; ++s)
#pragma unroll
                for (int c = 0; c < 4; ++c)
                    acc[s][c][r] += lred[wv][s * 32 + crow][c * 32 + l31];
        }
    } else if (wv == 4) {
        float tot = 0.f;
#pragma unroll
        for (int w = 0; w < 8; ++w) tot += sps[w][lane];
        sinv[lane] = 1.0f / tot;
    }
    __syncthreads();
    if (wv == 2 || wv == 3) {
#pragma unroll
        for (int r = 0; r < 16; ++r) {
            int crow = (r & 3) + 8 * (r >> 2) + 4 * hi;
#pragma unroll
            for (int s = 0; s < 2; ++s)
#pragma unroll
                for (int c = 0; c < 4; ++c)
                    lred[wv - 2][s * 32 + crow][c * 32 + l31] = acc[s][c][r];
        }
    }
    __syncthreads();
    if (wv < 2) {
#pragma unroll
        for (int r = 0; r < 16; ++r) {
            int crow = (r & 3) + 8 * (r >> 2) + 4 * hi;
#pragma unroll
            for (int s = 0; s < 2; ++s)
#pragma unroll
                for (int c = 0; c < 4; ++c)
                    acc[s][c][r] += lred[wv][s * 32 + crow][c * 32 + l31];
        }
    }
    __syncthreads();
    if (wv == 1) {
#pragma unroll
        for (int r = 0; r < 16; ++r) {
            int crow = (r & 3) + 8 * (r >> 2) + 4 * hi;
#pragma unroll
            for (int s = 0; s < 2; ++s)
#pragma unroll
                for (int c = 0; c < 4; ++c)
                    lred[0][s * 32 + crow][c * 32 + l31] = acc[s][c][r];
        }
    }
    __syncthreads();
    if (wv == 0) {
        const size_t obase = ((size_t)b * 2048 + (size_t)tile * 64) * 128;
#pragma unroll
        for (int r = 0; r < 16; ++r) {
            int crow = (r & 3) + 8 * (r >> 2) + 4 * hi;
#pragma unroll
            for (int s = 0; s < 2; ++s) {
                int row = s * 32 + crow;
                float iv = sinv[row];
#pragma unroll
                for (int c = 0; c < 4; ++c) {
                    float v = acc[s][c][r] + lred[0][row][c * 32 + l31];
                    out[obase + (size_t)row * 128 + c * 32 + l31] = v * iv;
                }
            }
        }
    }
}

extern "C" void kernel_launch(void* const* d_in, const int* in_sizes, int n_in,
                              void* d_out, int out_size, void* d_ws, size_t ws_size,
                              hipStream_t stream) {
    const float* x = (const float*)d_in[0];
    const float* W = (const float*)d_in[1];
    const float* a = (const float*)d_in[2];
    float* out = (float*)d_out;

    unsigned short* WT2h = (unsigned short*)d_ws;
    unsigned short* WT2l = WT2h + 128 * 128;
    unsigned short* HT2h = WT2l + 128 * 128;
    float* f1l = (float*)(HT2h + (size_t)8 * 128 * 2048);
    float* f2l = f1l + 16384;
    unsigned int* f2mk = (unsigned int*)(f2l + 16384);

    gat_wt<<<8, 256, 0, stream>>>(W, WT2h, WT2l, f2mk);
    gat_h<<<512, 256, 0, stream>>>(x, WT2h, WT2l, a, HT2h, f1l, f2l, f2mk);
    gat_attn<<<256, 512, 0, stream>>>(HT2h, f1l, f2l, f2mk, out);
}